// Round 3
// baseline (459.424 us; speedup 1.0000x reference)
//
#include <hip/hip_runtime.h>
#include <math.h>

// B=32, P=3, D=300, N=2048. Inputs x,y [B,P,D,N] f32; out [B,P*N,3] f32.
//
// R3 design: fix grid-limited occupancy (R2: 12 waves/CU, 31% occ).
// Block = 64 n (16 float4 quads) x 16 D-slices. tid: q = tid&15, s = tid>>4.
// Thread (q,s) accumulates rows d = s, s+16, ... (<300) for its 4 n.
//   -> grid = 3072 blocks = 12 blocks/CU -> 32 resident waves/CU.
// Loads: 16 consecutive lanes (one s-group... lanes of equal s) read 256 B
// contiguous. Manual depth-2 prefetch keeps 2 load-pairs (4 KB) in flight
// per wave. Reduce: shfl_down(32,16) within wave, 5 KB LDS across 4 waves.

constexpr int kB = 32;
constexpr int kP = 3;
constexpr int kD = 300;
constexpr int kN = 2048;
constexpr int kStride4 = kN / 4;   // 512 float4 per d-row

__device__ inline void fma4(float4& a, const float4 u, const float4 v) {
    a.x = fmaf(u.x, v.x, a.x); a.y = fmaf(u.y, v.y, a.y);
    a.z = fmaf(u.z, v.z, a.z); a.w = fmaf(u.w, v.w, a.w);
}
__device__ inline void red2(float4& v) {
    v.x += __shfl_down(v.x, 32); v.y += __shfl_down(v.y, 32);
    v.z += __shfl_down(v.z, 32); v.w += __shfl_down(v.w, 32);
    v.x += __shfl_down(v.x, 16); v.y += __shfl_down(v.y, 16);
    v.z += __shfl_down(v.z, 16); v.w += __shfl_down(v.w, 16);
}

__global__ __launch_bounds__(256, 8) void sim_measure_kernel(
    const float* __restrict__ x,
    const float* __restrict__ y,
    float* __restrict__ out)
{
    __shared__ float4 sm[4 * 16 * 5];        // [wave][quad][5 vals] = 5 KB

    const int tid = threadIdx.x;
    const int q   = tid & 15;                // n-quad within block's 64-n span
    const int s   = tid >> 4;                // D slice [0,16)
    const int bp  = blockIdx.x >> 5;         // 32 blocks per (b,p)
    const int n0  = (blockIdx.x & 31) << 6;  // base n for this block

    const size_t base = (size_t)bp * kD * kN + (size_t)(n0 + q * 4);
    const float4* __restrict__ xp = (const float4*)(x + base);
    const float4* __restrict__ yp = (const float4*)(y + base);

    float4 dot = {0,0,0,0}, xx = {0,0,0,0}, yy = {0,0,0,0},
           l2s = {0,0,0,0}, l1 = {0,0,0,0};

    // depth-2 register pipeline over rows d = s, s+16, ... (<300)
    float4 xv = xp[(size_t)s * kStride4];
    float4 yv = yp[(size_t)s * kStride4];
    for (int d = s + 16; d < kD; d += 16) {      // wave-uniform trip count
        const float4 xn = xp[(size_t)d * kStride4];
        const float4 yn = yp[(size_t)d * kStride4];
        fma4(dot, xv, yv); fma4(xx, xv, xv); fma4(yy, yv, yv);
        float4 df = {xv.x - yv.x, xv.y - yv.y, xv.z - yv.z, xv.w - yv.w};
        fma4(l2s, df, df);
        l1.x += fabsf(df.x); l1.y += fabsf(df.y);
        l1.z += fabsf(df.z); l1.w += fabsf(df.w);
        xv = xn; yv = yn;
    }
    fma4(dot, xv, yv); fma4(xx, xv, xv); fma4(yy, yv, yv);
    {
        float4 df = {xv.x - yv.x, xv.y - yv.y, xv.z - yv.z, xv.w - yv.w};
        fma4(l2s, df, df);
        l1.x += fabsf(df.x); l1.y += fabsf(df.y);
        l1.z += fabsf(df.z); l1.w += fabsf(df.w);
    }

    // combine 4 slices within each wave -> lanes 0..15 hold wave partials
    red2(dot); red2(xx); red2(yy); red2(l2s); red2(l1);

    const int wv = tid >> 6;                 // wave id [0,4)
    if ((tid & 63) < 16) {
        const int qq = tid & 15;
        float4* p = &sm[(wv * 16 + qq) * 5];
        p[0] = dot; p[1] = xx; p[2] = yy; p[3] = l2s; p[4] = l1;
    }
    __syncthreads();

    if (tid < 16) {
        float4 D = {0,0,0,0}, X = {0,0,0,0}, Y = {0,0,0,0},
               E = {0,0,0,0}, A = {0,0,0,0};
        #pragma unroll
        for (int w = 0; w < 4; ++w) {
            const float4* p = &sm[(w * 16 + tid) * 5];
            float4 a = p[0], b = p[1], c = p[2], e = p[3], f = p[4];
            D.x += a.x; D.y += a.y; D.z += a.z; D.w += a.w;
            X.x += b.x; X.y += b.y; X.z += b.z; X.w += b.w;
            Y.x += c.x; Y.y += c.y; Y.z += c.z; Y.w += c.w;
            E.x += e.x; E.y += e.y; E.z += e.z; E.w += e.w;
            A.x += f.x; A.y += f.y; A.z += f.z; A.w += f.w;
        }
        const float c0 = D.x / (sqrtf(X.x) * sqrtf(Y.x));
        const float c1 = D.y / (sqrtf(X.y) * sqrtf(Y.y));
        const float c2 = D.z / (sqrtf(X.z) * sqrtf(Y.z));
        const float c3 = D.w / (sqrtf(X.w) * sqrtf(Y.w));
        const float e0 = sqrtf(E.x), e1 = sqrtf(E.y),
                    e2 = sqrtf(E.z), e3 = sqrtf(E.w);

        float4 o0 = {c0,  e0,  A.x, c1};
        float4 o1 = {e1,  A.y, c2,  e2};
        float4 o2 = {A.z, c3,  e3,  A.w};
        // (bp*N + n0 + q*4)*3 is a multiple of 12 -> 16B aligned
        float4* op = (float4*)(out + ((size_t)bp * kN + (size_t)(n0 + tid * 4)) * 3);
        op[0] = o0; op[1] = o1; op[2] = o2;
    }
}

extern "C" void kernel_launch(void* const* d_in, const int* in_sizes, int n_in,
                              void* d_out, int out_size, void* d_ws, size_t ws_size,
                              hipStream_t stream)
{
    const float* x = (const float*)d_in[0];
    const float* y = (const float*)d_in[1];
    float* out = (float*)d_out;

    const int grid = kB * kP * (kN / 64);    // 3072 blocks, 64 n each
    sim_measure_kernel<<<grid, 256, 0, stream>>>(x, y, out);
}